// Round 1
// baseline (373.138 us; speedup 1.0000x reference)
//
#include <hip/hip_runtime.h>

typedef _Float16 h8 __attribute__((ext_vector_type(8)));
typedef _Float16 h4 __attribute__((ext_vector_type(4)));
typedef float f4 __attribute__((ext_vector_type(4)));

typedef __attribute__((address_space(1))) const void GV;
typedef __attribute__((address_space(3))) void SV;

__device__ __forceinline__ void async16(const void* g, void* s) {
  __builtin_amdgcn_global_load_lds((GV*)g, (SV*)s, 16, 0, 0);
}

__device__ __forceinline__ float readlane_f(float v, int l) {
  return __uint_as_float(__builtin_amdgcn_readlane(__float_as_uint(v), l));
}

// sizes
// x: (4,4096,1024) fp32   -> M=16384, K=1024
// w_qkv: (3072,1024) fp32 -> N=3072 (e = h*192 + d*3 + t)
// mem_kv: (2,16,4,64) fp32
// mask: (4,4096) int32
// out: (4,4096,1024) fp32

#define X4N 4194304   // 16777216/4
#define W4N 786432    // 3145728/4

// ---------------- kernel 1: fp32 -> f16 convert (x then w) ----------------
__global__ __launch_bounds__(256) void cvt_f16(const float4* __restrict__ x,
                                               const float4* __restrict__ w,
                                               h4* __restrict__ xh,
                                               h4* __restrict__ wh) {
  int i = blockIdx.x * 256 + threadIdx.x;
  if (i < X4N) {
    float4 v = x[i];
    h4 o = {(_Float16)v.x, (_Float16)v.y, (_Float16)v.z, (_Float16)v.w};
    xh[i] = o;
  } else {
    int j = i - X4N;
    float4 v = w[j];
    h4 o = {(_Float16)v.x, (_Float16)v.y, (_Float16)v.z, (_Float16)v.w};
    wh[j] = o;
  }
}

// ---------------- kernel 2: qkv = x @ w^T, f16 MFMA (m97 structure) ------
// grid (24, 128): bx = n-tile, by = m-tile. 256 thr = 4 waves, 64x64 per wave.
__global__ __launch_bounds__(256, 3) void gemm_qkv(const _Float16* __restrict__ A,
                                                   const _Float16* __restrict__ B,
                                                   _Float16* __restrict__ C) {
  __shared__ _Float16 As[128 * 32];
  __shared__ _Float16 Bs[128 * 32];
  const int tid = threadIdx.x;
  const int lane = tid & 63, wid = tid >> 6;
  const int wm = wid & 1, wn = wid >> 1;
  const int l15 = lane & 15, quad = lane >> 4;
  const int m0 = blockIdx.y * 128, n0 = blockIdx.x * 128;

  const f4 z = {0.f, 0.f, 0.f, 0.f};
  f4 acc[4][4];
#pragma unroll
  for (int i = 0; i < 4; ++i)
#pragma unroll
    for (int j = 0; j < 4; ++j) acc[i][j] = z;

  for (int kt = 0; kt < 32; ++kt) {
    const int k0 = kt * 32;
#pragma unroll
    for (int it = 0; it < 2; ++it) {
      const int c = wid + it * 4;         // 8 chunks of 1KB per tile
      const int idx = c * 64 + lane;      // 0..511
      const int row = idx >> 2, cg = idx & 3;
      async16(A + ((size_t)(m0 + row) * 1024 + k0 + cg * 8), As + c * 512);
      async16(B + ((size_t)(n0 + row) * 1024 + k0 + cg * 8), Bs + c * 512);
    }
    __syncthreads();
    h8 af[4], bf[4];
#pragma unroll
    for (int i = 0; i < 4; ++i)
      af[i] = *(const h8*)&As[(wm * 64 + i * 16 + l15) * 32 + quad * 8];
#pragma unroll
    for (int j = 0; j < 4; ++j)
      bf[j] = *(const h8*)&Bs[(wn * 64 + j * 16 + l15) * 32 + quad * 8];
#pragma unroll
    for (int i = 0; i < 4; ++i)
#pragma unroll
      for (int j = 0; j < 4; ++j)
        acc[i][j] = __builtin_amdgcn_mfma_f32_16x16x32_f16(af[i], bf[j], acc[i][j], 0, 0, 0);
    __syncthreads();
  }
  // epilogue: C layout col=lane&15, row=quad*4+reg  (f16 store)
#pragma unroll
  for (int i = 0; i < 4; ++i) {
    const int r0 = m0 + wm * 64 + i * 16 + quad * 4;
#pragma unroll
    for (int j = 0; j < 4; ++j) {
      const int cc = n0 + wn * 64 + j * 16 + l15;
#pragma unroll
      for (int r = 0; r < 4; ++r)
        C[(size_t)(r0 + r) * 3072 + cc] = (_Float16)acc[i][j][r];
    }
  }
}

// ---------------- kernel 3: split-K context partials ----------------------
// grid (16, 64): bx = seq chunk (256 rows), by = bh. part layout per block:
// 4096 acc[d][e] + 64 den[d] (4160 floats)
#define ACC_ROW(rr) { \
    h4 ekv = *(const h4*)&ekb[(rr) * 64 + d0]; \
    h4 vv4 = *(const h4*)&vb[(rr) * 64 + e0]; \
    float ef[4], vf[4]; \
    _Pragma("unroll") for (int ii = 0; ii < 4; ++ii) { ef[ii] = (float)ekv[ii]; vf[ii] = (float)vv4[ii]; } \
    _Pragma("unroll") for (int di = 0; di < 4; ++di) \
      _Pragma("unroll") for (int ei = 0; ei < 4; ++ei) \
        acc[di * 4 + ei] += ef[di] * vf[ei]; }

__global__ __launch_bounds__(256) void ctx_partial(const _Float16* __restrict__ qkv,
                                                   const float* __restrict__ memkv,
                                                   const int* __restrict__ mask,
                                                   float* __restrict__ part) {
  const int chunk = blockIdx.x;  // 0..15
  const int bh = blockIdx.y;     // 0..63
  const int b = bh >> 4, h = bh & 15;
  const int tid = threadIdx.x;
  const int lane = tid & 63, wid = tid >> 6;

  __shared__ _Float16 raw[32 * 192];
  __shared__ _Float16 ekb[32 * 64];
  __shared__ _Float16 vb[32 * 64];
  __shared__ int lmask[32];
  __shared__ float denr[256];

  const int dg = tid >> 4, eg = tid & 15;
  const int d0 = dg * 4, e0 = eg * 4;
  const int du = tid & 63;            // unpack: d index
  const int rbase = (tid >> 6) * 8;   // unpack: 8 rows

  float acc[16];
#pragma unroll
  for (int i = 0; i < 16; ++i) acc[i] = 0.f;
  float dpart = 0.f;

  const size_t rowbase = (size_t)b * 4096;

  for (int bi = 0; bi < 8; ++bi) {
    const int lb = chunk * 256 + bi * 32;
    // stage 32 rows x 384B spans (k,v interleaved with q) -> 12 x 1KB chunks
#pragma unroll
    for (int it = 0; it < 3; ++it) {
      const int c = wid + it * 4;
      const int idx = c * 64 + lane;  // 0..767
      const int r = idx / 24;
      const int cc = idx - r * 24;
      async16(qkv + ((rowbase + lb + r) * 3072 + h * 192 + cc * 8), raw + c * 512);
    }
    if (tid < 32) lmask[tid] = mask[rowbase + lb + tid];
    __syncthreads();
    // unpack: ek = exp(k) (0 if masked), copy v; both f16
#pragma unroll
    for (int k = 0; k < 8; ++k) {
      const int r = rbase + k;
      const int mk = lmask[r];
      const float kf = (float)raw[r * 192 + 3 * du + 1];
      const _Float16 vh = raw[r * 192 + 3 * du + 2];
      const float ek = mk ? __expf(kf) : 0.f;
      const _Float16 ekh = (_Float16)ek;
      ekb[r * 64 + du] = ekh;
      vb[r * 64 + du] = mk ? vh : (_Float16)0.f;
      dpart += (float)ekh;
    }
    __syncthreads();
#pragma unroll 4
    for (int r = 0; r < 32; ++r) ACC_ROW(r)
    __syncthreads();
  }

  // learned memory kv rows (always unmasked) handled once, in chunk 0
  if (chunk == 0) {
    const int j = tid >> 6, d = tid & 63;
    const float mkf = memkv[h * 256 + j * 64 + d];
    const float mvf = memkv[4096 + h * 256 + j * 64 + d];
    const float ek = __expf(mkf);
    const _Float16 ekh = (_Float16)ek;
    ekb[j * 64 + d] = ekh;
    vb[j * 64 + d] = (_Float16)mvf;
    dpart += (float)ekh;
    __syncthreads();
#pragma unroll
    for (int r = 0; r < 4; ++r) ACC_ROW(r)
  }

  denr[tid] = dpart;
  __syncthreads();

  const size_t pb = ((size_t)bh * 16 + chunk) * 4160;
  if (tid < 64) {
    const float s = denr[tid] + denr[tid + 64] + denr[tid + 128] + denr[tid + 192];
    part[pb + 4096 + tid] = s;
  }
#pragma unroll
  for (int di = 0; di < 4; ++di) {
    f4 v = {acc[di * 4 + 0], acc[di * 4 + 1], acc[di * 4 + 2], acc[di * 4 + 3]};
    *(f4*)&part[pb + (size_t)(d0 + di) * 64 + e0] = v;
  }
}

// ---------------- kernel 4: reduce partials, divide by den ---------------
__global__ __launch_bounds__(256) void reduce_ctx(const float* __restrict__ part,
                                                  float* __restrict__ ctx) {
  const int bh = blockIdx.x;
  const int tid = threadIdx.x;
  __shared__ float dl[64];
  const size_t pb = (size_t)bh * 16 * 4160;
  if (tid < 64) {
    float s = 0.f;
#pragma unroll
    for (int c = 0; c < 16; ++c) s += part[pb + (size_t)c * 4160 + 4096 + tid];
    dl[tid] = s;
  }
  __syncthreads();
  const int dg = tid >> 4, eg = tid & 15;
  const int d0 = dg * 4, e0 = eg * 4;
#pragma unroll
  for (int di = 0; di < 4; ++di) {
    f4 s = {0.f, 0.f, 0.f, 0.f};
#pragma unroll
    for (int c = 0; c < 16; ++c)
      s += *(const f4*)&part[pb + (size_t)c * 4160 + (size_t)(d0 + di) * 64 + e0];
    const float inv = 1.0f / dl[d0 + di];
    s *= inv;
    *(f4*)&ctx[(size_t)bh * 4096 + (size_t)(d0 + di) * 64 + e0] = s;
  }
}

// ---------------- kernel 5: q-softmax @ ctx, mask, write out -------------
// grid (32, 64): bx = 128-row chunk, by = bh. Each wave: 32 rows, lane = e.
__global__ __launch_bounds__(256) void attn_out(const _Float16* __restrict__ qkv,
                                                const float* __restrict__ ctx,
                                                const int* __restrict__ mask,
                                                float* __restrict__ out) {
  const int bh = blockIdx.y;
  const int b = bh >> 4, h = bh & 15;
  const int lane = threadIdx.x & 63, wid = threadIdx.x >> 6;

  float creg[64];  // ctx column e=lane, all d, in VGPRs
  const float* cb = ctx + (size_t)bh * 4096 + lane;
#pragma unroll
  for (int d = 0; d < 64; ++d) creg[d] = cb[d * 64];

  const int l0 = blockIdx.x * 128 + wid * 32;
  const size_t rowbase = (size_t)b * 4096;

  for (int rr = 0; rr < 32; ++rr) {
    const int l = l0 + rr;
    const size_t row = rowbase + l;
    float* op = out + row * 1024 + h * 64 + lane;
    const int mk = mask[row];  // wave-uniform
    if (mk == 0) { *op = 0.f; continue; }
    const float q = (float)qkv[row * 3072 + h * 192 + 3 * lane];
    const float w = __expf(q * 0.125f);  // SCALE = 1/8; logits tiny, no max needed
    float s = w;
#pragma unroll
    for (int k = 1; k < 64; k <<= 1) s += __shfl_xor(s, k);
    float a0 = 0.f, a1 = 0.f, a2 = 0.f, a3 = 0.f;
#pragma unroll
    for (int d = 0; d < 64; d += 4) {
      a0 += readlane_f(w, d + 0) * creg[d + 0];
      a1 += readlane_f(w, d + 1) * creg[d + 1];
      a2 += readlane_f(w, d + 2) * creg[d + 2];
      a3 += readlane_f(w, d + 3) * creg[d + 3];
    }
    *op = ((a0 + a1) + (a2 + a3)) / s;
  }
}

// ---------------- launch ----------------
extern "C" void kernel_launch(void* const* d_in, const int* in_sizes, int n_in,
                              void* d_out, int out_size, void* d_ws, size_t ws_size,
                              hipStream_t stream) {
  const float* x = (const float*)d_in[0];      // 16777216
  const float* w = (const float*)d_in[1];      // 3145728
  const float* memkv = (const float*)d_in[2];  // 8192
  const int* mask = (const int*)d_in[3];       // 16384
  float* out = (float*)d_out;

  char* ws = (char*)d_ws;
  _Float16* xh  = (_Float16*)(ws + 0);          //  33,554,432 B
  _Float16* wh  = (_Float16*)(ws + 33554432);   //   6,291,456 B
  _Float16* qkv = (_Float16*)(ws + 39845888);   // 100,663,296 B
  float* part   = (float*)(ws + 140509184);     //  17,039,360 B
  float* ctx    = (float*)(ws + 157548544);     //   1,048,576 B  (total ~151 MiB)

  cvt_f16<<<dim3(19456), dim3(256), 0, stream>>>((const float4*)x, (const float4*)w,
                                                 (h4*)xh, (h4*)wh);
  gemm_qkv<<<dim3(24, 128), dim3(256), 0, stream>>>(xh, wh, qkv);
  ctx_partial<<<dim3(16, 64), dim3(256), 0, stream>>>(qkv, memkv, mask, part);
  reduce_ctx<<<dim3(64), dim3(256), 0, stream>>>(part, ctx);
  attn_out<<<dim3(32, 64), dim3(256), 0, stream>>>(qkv, ctx, mask, out);
}

// Round 2
// 338.955 us; speedup vs baseline: 1.1009x; 1.1009x over previous
//
#include <hip/hip_runtime.h>

typedef _Float16 h8 __attribute__((ext_vector_type(8)));
typedef _Float16 h4 __attribute__((ext_vector_type(4)));
typedef float f4 __attribute__((ext_vector_type(4)));

typedef __attribute__((address_space(1))) const void GV;
typedef __attribute__((address_space(3))) void SV;

__device__ __forceinline__ void async16(const void* g, void* s) {
  __builtin_amdgcn_global_load_lds((GV*)g, (SV*)s, 16, 0, 0);
}

// sizes:
// x: (4,4096,1024) fp32   -> M=16384 rows, K=1024
// w_qkv: (3072,1024) fp32 -> rows e = h*192 + d*3 + t
// mem_kv: (2,16,4,64) fp32
// mask: (4,4096) int32
// out: (4,4096,1024) fp32

#define X4N 4194304   // 16777216/4
#define W4N 786432    // 3145728/4

// ---------------- kernel 1: fp32 -> f16 convert (x then w) ----------------
__global__ __launch_bounds__(256) void cvt_f16(const float4* __restrict__ x,
                                               const float4* __restrict__ w,
                                               h4* __restrict__ xh,
                                               h4* __restrict__ wh) {
  int i = blockIdx.x * 256 + threadIdx.x;
  if (i < X4N) {
    float4 v = x[i];
    h4 o = {(_Float16)v.x, (_Float16)v.y, (_Float16)v.z, (_Float16)v.w};
    xh[i] = o;
  } else {
    int j = i - X4N;
    float4 v = w[j];
    h4 o = {(_Float16)v.x, (_Float16)v.y, (_Float16)v.z, (_Float16)v.w};
    wh[j] = o;
  }
}

// ---------------- kernel 2: qkv GEMM, 128x192 tile = one head ------------
// grid (16 heads, 128 m-tiles). 4 waves: wm=wid&1 (64 rows), wn=wid>>1 (96 cols).
// Epilogue fuses exp + deinterleave: P = exp(q/8), EK = mask?exp(k):0, V = v,
// each stored f16 [row, h*64+d] (row-contiguous d).
__global__ __launch_bounds__(256, 2) void gemm_qkv(const _Float16* __restrict__ A,
                                                   const _Float16* __restrict__ W,
                                                   const int* __restrict__ mask,
                                                   _Float16* __restrict__ P,
                                                   _Float16* __restrict__ EK,
                                                   _Float16* __restrict__ V) {
  __shared__ _Float16 As[128 * 32];   // 8 KB
  __shared__ _Float16 Bs[192 * 32];   // 12 KB
  const int tid = threadIdx.x;
  const int lane = tid & 63, wid = tid >> 6;
  const int wm = wid & 1, wn = wid >> 1;
  const int l15 = lane & 15, quad = lane >> 4;
  const int h = blockIdx.x;
  const int m0 = blockIdx.y * 128;

  const f4 z = {0.f, 0.f, 0.f, 0.f};
  f4 acc[4][6];
#pragma unroll
  for (int i = 0; i < 4; ++i)
#pragma unroll
    for (int j = 0; j < 6; ++j) acc[i][j] = z;

  for (int kt = 0; kt < 32; ++kt) {
    const int k0 = kt * 32;
#pragma unroll
    for (int it = 0; it < 5; ++it) {
      const int idx = it * 256 + tid;    // 0..1279
      if (idx < 512) {                   // A: 128 rows x 4 chunks
        const int row = idx >> 2, cg = idx & 3;
        async16(A + ((size_t)(m0 + row) * 1024 + k0 + cg * 8), As + idx * 8);
      } else {                           // B: 192 rows x 4 chunks
        const int j = idx - 512;
        const int row = j >> 2, cg = j & 3;
        async16(W + ((size_t)(h * 192 + row) * 1024 + k0 + cg * 8), Bs + j * 8);
      }
    }
    __syncthreads();
    h8 af[4], bf[6];
#pragma unroll
    for (int i = 0; i < 4; ++i)
      af[i] = *(const h8*)&As[(wm * 64 + i * 16 + l15) * 32 + quad * 8];
#pragma unroll
    for (int j = 0; j < 6; ++j)
      bf[j] = *(const h8*)&Bs[(wn * 96 + j * 16 + l15) * 32 + quad * 8];
#pragma unroll
    for (int i = 0; i < 4; ++i)
#pragma unroll
      for (int j = 0; j < 6; ++j)
        acc[i][j] = __builtin_amdgcn_mfma_f32_16x16x32_f16(af[i], bf[j], acc[i][j], 0, 0, 0);
    __syncthreads();
  }

  // epilogue: col cl in [0,192): d = cl/3, t = cl%3 -> scatter to P/EK/V
  const size_t hb = (size_t)h * 64;
#pragma unroll
  for (int i = 0; i < 4; ++i) {
    const int r0 = m0 + wm * 64 + i * 16 + quad * 4;
#pragma unroll
    for (int j = 0; j < 6; ++j) {
      const int cl = wn * 96 + j * 16 + l15;
      const int d = (cl * 21846) >> 16;
      const int t = cl - 3 * d;
      _Float16* dst = (t == 0) ? P : ((t == 1) ? EK : V);
#pragma unroll
      for (int r = 0; r < 3 + 1; ++r) {
        const int row = r0 + r;
        const float v = acc[i][j][r];
        const int mk = mask[row];
        const float ev = __expf(t == 0 ? v * 0.125f : v);
        const float o = (t == 0) ? ev : ((t == 1) ? (mk ? ev : 0.f) : v);
        dst[(size_t)row * 1024 + hb + d] = (_Float16)o;
      }
    }
  }
}

// ---------------- kernel 3: ctx partials via MFMA ------------------------
// grid (16 chunks, 64 bh). D[d][e] = sum_n EK[n,d]*V[n,e]; ones-col -> den[d].
// Wave w covers d in [16w,16w+16). Partials f32 [bh][chunk][4096 + 64den].
__global__ __launch_bounds__(256) void ctx_partial(const _Float16* __restrict__ EK,
                                                   const _Float16* __restrict__ V,
                                                   const float* __restrict__ memkv,
                                                   float* __restrict__ part) {
  const int chunk = blockIdx.x;  // 0..15
  const int bh = blockIdx.y;     // 0..63
  const int b = bh >> 4, h = bh & 15;
  const int tid = threadIdx.x;
  const int lane = tid & 63, wid = tid >> 6;
  const int l15 = lane & 15, quad = lane >> 4;

  __shared__ _Float16 ekb[32 * 64];  // 4 KB
  __shared__ _Float16 vb[32 * 64];   // 4 KB

  const f4 z = {0.f, 0.f, 0.f, 0.f};
  f4 acc[5];
#pragma unroll
  for (int i = 0; i < 5; ++i) acc[i] = z;

  h8 bones;
  {
    const _Float16 o1 = (l15 == 0) ? (_Float16)1.f : (_Float16)0.f;
#pragma unroll
    for (int j = 0; j < 8; ++j) bones[j] = o1;
  }
  const int dloc = wid * 16 + l15;
  const int srow = tid >> 3, scg = tid & 7;

  for (int bi = 0; bi < 8; ++bi) {
    const int l0 = chunk * 256 + bi * 32;
    const size_t so = (size_t)(b * 4096 + l0 + srow) * 1024 + h * 64 + scg * 8;
    async16(EK + so, ekb + tid * 8);
    async16(V + so, vb + tid * 8);
    __syncthreads();
    h8 a, bf[4];
#pragma unroll
    for (int j = 0; j < 8; ++j) a[j] = ekb[(quad * 8 + j) * 64 + dloc];
#pragma unroll
    for (int et = 0; et < 4; ++et)
#pragma unroll
      for (int j = 0; j < 8; ++j) bf[et][j] = vb[(quad * 8 + j) * 64 + et * 16 + l15];
#pragma unroll
    for (int et = 0; et < 4; ++et)
      acc[et] = __builtin_amdgcn_mfma_f32_16x16x32_f16(a, bf[et], acc[et], 0, 0, 0);
    acc[4] = __builtin_amdgcn_mfma_f32_16x16x32_f16(a, bones, acc[4], 0, 0, 0);
    __syncthreads();
  }

  // memory kv rows (4, always unmasked) appended once by chunk 0
  if (chunk == 0) {
    *(h8*)&ekb[tid * 8] = h8{0, 0, 0, 0, 0, 0, 0, 0};  // zero all 32 rows
    __syncthreads();
    {
      const int j = tid >> 6, d = tid & 63;
      ekb[j * 64 + d] = (_Float16)__expf(memkv[(h * 4 + j) * 64 + d]);
      vb[j * 64 + d] = (_Float16)memkv[4096 + (h * 4 + j) * 64 + d];
    }
    __syncthreads();
    h8 a, bf[4];
#pragma unroll
    for (int j = 0; j < 8; ++j) a[j] = ekb[(quad * 8 + j) * 64 + dloc];
#pragma unroll
    for (int et = 0; et < 4; ++et)
#pragma unroll
      for (int j = 0; j < 8; ++j) bf[et][j] = vb[(quad * 8 + j) * 64 + et * 16 + l15];
#pragma unroll
    for (int et = 0; et < 4; ++et)
      acc[et] = __builtin_amdgcn_mfma_f32_16x16x32_f16(a, bf[et], acc[et], 0, 0, 0);
    acc[4] = __builtin_amdgcn_mfma_f32_16x16x32_f16(a, bones, acc[4], 0, 0, 0);
  }

  const size_t pb = ((size_t)bh * 16 + chunk) * 4160;
  const int dw = wid * 16 + quad * 4;
#pragma unroll
  for (int et = 0; et < 4; ++et)
#pragma unroll
    for (int r = 0; r < 4; ++r)
      part[pb + (size_t)(dw + r) * 64 + et * 16 + l15] = acc[et][r];
  if (l15 == 0) {
#pragma unroll
    for (int r = 0; r < 4; ++r) part[pb + 4096 + dw + r] = acc[4][r];
  }
}

// ---------------- kernel 4: reduce partials, divide, store ctx f16 -------
__global__ __launch_bounds__(256) void reduce_ctx(const float* __restrict__ part,
                                                  _Float16* __restrict__ ctxh) {
  const int bh = blockIdx.x;
  const int tid = threadIdx.x;
  __shared__ float inv[64];
  const size_t pb = (size_t)bh * 16 * 4160;
  if (tid < 64) {
    float s = 0.f;
#pragma unroll
    for (int c = 0; c < 16; ++c) s += part[pb + (size_t)c * 4160 + 4096 + tid];
    inv[tid] = 1.0f / s;
  }
  __syncthreads();
  const int d = tid >> 2, e0 = (tid & 3) * 16;
  f4 s[4];
#pragma unroll
  for (int g = 0; g < 4; ++g) s[g] = f4{0.f, 0.f, 0.f, 0.f};
#pragma unroll
  for (int c = 0; c < 16; ++c)
#pragma unroll
    for (int g = 0; g < 4; ++g)
      s[g] += *(const f4*)&part[pb + (size_t)c * 4160 + (size_t)d * 64 + e0 + g * 4];
  const float iv = inv[d];
#pragma unroll
  for (int g = 0; g < 4; ++g) {
    h4 o = {(_Float16)(s[g][0] * iv), (_Float16)(s[g][1] * iv),
            (_Float16)(s[g][2] * iv), (_Float16)(s[g][3] * iv)};
    *(h4*)&ctxh[(size_t)bh * 4096 + (size_t)d * 64 + e0 + g * 4] = o;
  }
}

// ---------------- kernel 5: out = (P @ ctx)/s via MFMA, ones-col for s ---
// grid (128 l-chunks, 16 heads). Block: 128 rows x 64 e. Wave: 32 rows.
__global__ __launch_bounds__(256) void attn_out(const _Float16* __restrict__ P,
                                                const _Float16* __restrict__ ctxh,
                                                const int* __restrict__ mask,
                                                float* __restrict__ out) {
  const int l0 = blockIdx.x * 128;
  const int h = blockIdx.y;
  const int bh = (l0 >> 12) * 16 + h;
  const int tid = threadIdx.x;
  const int lane = tid & 63, wid = tid >> 6;
  const int l15 = lane & 15, quad = lane >> 4;

  __shared__ _Float16 pl[128 * 64];  // 16 KB
  __shared__ _Float16 cl[64 * 64];   // 8 KB

#pragma unroll
  for (int it = 0; it < 4; ++it) {
    const int idx = it * 256 + tid;
    const int row = idx >> 3, cg = idx & 7;
    async16(P + ((size_t)(l0 + row) * 1024 + h * 64 + cg * 8), pl + idx * 8);
  }
#pragma unroll
  for (int it = 0; it < 2; ++it) {
    const int idx = it * 256 + tid;
    async16(ctxh + ((size_t)bh * 4096 + idx * 8), cl + idx * 8);
  }
  __syncthreads();

  h8 af[2][2], bf[2][4], bones;
  {
    const _Float16 o1 = (l15 == 0) ? (_Float16)1.f : (_Float16)0.f;
#pragma unroll
    for (int j = 0; j < 8; ++j) bones[j] = o1;
  }
#pragma unroll
  for (int i = 0; i < 2; ++i)
#pragma unroll
    for (int ks = 0; ks < 2; ++ks)
      af[i][ks] = *(const h8*)&pl[(wid * 32 + i * 16 + l15) * 64 + ks * 32 + quad * 8];
#pragma unroll
  for (int ks = 0; ks < 2; ++ks)
#pragma unroll
    for (int et = 0; et < 4; ++et)
#pragma unroll
      for (int j = 0; j < 8; ++j)
        bf[ks][et][j] = cl[(ks * 32 + quad * 8 + j) * 64 + et * 16 + l15];

  const f4 z = {0.f, 0.f, 0.f, 0.f};
  f4 acc[2][5];
#pragma unroll
  for (int i = 0; i < 2; ++i)
#pragma unroll
    for (int j = 0; j < 5; ++j) acc[i][j] = z;
#pragma unroll
  for (int i = 0; i < 2; ++i)
#pragma unroll
    for (int ks = 0; ks < 2; ++ks) {
#pragma unroll
      for (int et = 0; et < 4; ++et)
        acc[i][et] = __builtin_amdgcn_mfma_f32_16x16x32_f16(af[i][ks], bf[ks][et], acc[i][et], 0, 0, 0);
      acc[i][4] = __builtin_amdgcn_mfma_f32_16x16x32_f16(af[i][ks], bones, acc[i][4], 0, 0, 0);
    }

#pragma unroll
  for (int i = 0; i < 2; ++i) {
#pragma unroll
    for (int r = 0; r < 4; ++r) {
      const int row = l0 + wid * 32 + i * 16 + quad * 4 + r;
      const float sb = __shfl(acc[i][4][r], lane & 48);  // den from col-0 lane
      const int mk = mask[row];
      const float iv = mk ? 1.0f / sb : 0.0f;
#pragma unroll
      for (int et = 0; et < 4; ++et)
        out[(size_t)row * 1024 + h * 64 + et * 16 + l15] = acc[i][et][r] * iv;
    }
  }
}

// ---------------- launch ----------------
extern "C" void kernel_launch(void* const* d_in, const int* in_sizes, int n_in,
                              void* d_out, int out_size, void* d_ws, size_t ws_size,
                              hipStream_t stream) {
  const float* x = (const float*)d_in[0];      // 16777216
  const float* w = (const float*)d_in[1];      // 3145728
  const float* memkv = (const float*)d_in[2];  // 8192
  const int* mask = (const int*)d_in[3];       // 16384
  float* out = (float*)d_out;

  char* ws = (char*)d_ws;
  _Float16* xh   = (_Float16*)(ws + 0);           //  33,554,432
  _Float16* wh   = (_Float16*)(ws + 33554432);    //   6,291,456
  _Float16* P    = (_Float16*)(ws + 39845888);    //  33,554,432
  _Float16* EK   = (_Float16*)(ws + 73400320);    //  33,554,432
  _Float16* V    = (_Float16*)(ws + 106954752);   //  33,554,432
  float*    part = (float*)(ws + 140509184);      //  17,039,360
  _Float16* ctxh = (_Float16*)(ws + 157548544);   //     524,288  (~150.8 MB)

  cvt_f16<<<dim3(19456), dim3(256), 0, stream>>>((const float4*)x, (const float4*)w,
                                                 (h4*)xh, (h4*)wh);
  gemm_qkv<<<dim3(16, 128), dim3(256), 0, stream>>>(xh, wh, mask, P, EK, V);
  ctx_partial<<<dim3(16, 64), dim3(256), 0, stream>>>(EK, V, memkv, part);
  reduce_ctx<<<dim3(64), dim3(256), 0, stream>>>(part, ctxh);
  attn_out<<<dim3(128, 16), dim3(256), 0, stream>>>(P, ctxh, mask, out);
}

// Round 3
// 337.760 us; speedup vs baseline: 1.1047x; 1.0035x over previous
//
#include <hip/hip_runtime.h>

typedef _Float16 h8 __attribute__((ext_vector_type(8)));
typedef _Float16 h4 __attribute__((ext_vector_type(4)));
typedef float f4 __attribute__((ext_vector_type(4)));

typedef __attribute__((address_space(1))) const void GV;
typedef __attribute__((address_space(3))) void SV;

__device__ __forceinline__ void async16(const void* g, void* s) {
  __builtin_amdgcn_global_load_lds((GV*)g, (SV*)s, 16, 0, 0);
}

// sizes:
// x: (4,4096,1024) fp32   -> M=16384 rows, K=1024
// w_qkv: (3072,1024) fp32 -> rows e = h*192 + d*3 + t
// mem_kv: (2,16,4,64) fp32
// mask: (4,4096) int32
// out: (4,4096,1024) fp32
//
// Layouts produced by gemm:
//   P   [row 0..16384) * 1024 + h*64 + d      (f16, exp(q/8))   n-major, d-contig
//   EKt [(b*16+h)*64 + d] * 4096 + l          (f16, mask?exp(k):0)  d-major, n-contig
//   Vt  [(b*16+h)*64 + d] * 4096 + l          (f16, v)              d-major, n-contig
// d-major EK/V makes MFMA A/B fragments 16-B contiguous in GLOBAL memory ->
// ctx kernel needs no LDS at all.

#define X4N 4194304   // 16777216/4

// ---------------- kernel 1: fp32 -> f16 convert (x then w) ----------------
__global__ __launch_bounds__(256) void cvt_f16(const float4* __restrict__ x,
                                               const float4* __restrict__ w,
                                               h4* __restrict__ xh,
                                               h4* __restrict__ wh) {
  int i = blockIdx.x * 256 + threadIdx.x;
  if (i < X4N) {
    float4 v = x[i];
    h4 o = {(_Float16)v.x, (_Float16)v.y, (_Float16)v.z, (_Float16)v.w};
    xh[i] = o;
  } else {
    int j = i - X4N;
    float4 v = w[j];
    h4 o = {(_Float16)v.x, (_Float16)v.y, (_Float16)v.z, (_Float16)v.w};
    wh[j] = o;
  }
}

// ---------------- kernel 2: qkv GEMM 128x128, fused exp + deinterleave ---
// grid (24,128) flat-swizzled: y = f%128 so all 24 blocks sharing an A-tile
// get the same f%8 -> same XCD -> A-tile lives in ONE L2.
__global__ __launch_bounds__(256, 4) void gemm_qkv(const _Float16* __restrict__ A,
                                                   const _Float16* __restrict__ W,
                                                   const int* __restrict__ mask,
                                                   _Float16* __restrict__ P,
                                                   _Float16* __restrict__ EKt,
                                                   _Float16* __restrict__ Vt) {
  __shared__ _Float16 As[128 * 32];   // 8 KB
  __shared__ _Float16 Bs[128 * 32];   // 8 KB
  const int tid = threadIdx.x;
  const int lane = tid & 63, wid = tid >> 6;
  const int wm = wid & 1, wn = wid >> 1;
  const int l15 = lane & 15, quad = lane >> 4;
  const int f = blockIdx.x + 24 * blockIdx.y;
  const int m0 = (f % 128) * 128;
  const int n0 = (f / 128) * 128;

  const f4 z = {0.f, 0.f, 0.f, 0.f};
  f4 acc[4][4];
#pragma unroll
  for (int i = 0; i < 4; ++i)
#pragma unroll
    for (int j = 0; j < 4; ++j) acc[i][j] = z;

  for (int kt = 0; kt < 32; ++kt) {
    const int k0 = kt * 32;
#pragma unroll
    for (int it = 0; it < 2; ++it) {
      const int c = wid + it * 4;         // 8 chunks of 1KB per tile
      const int idx = c * 64 + lane;      // 0..511
      const int row = idx >> 2, cg = idx & 3;
      async16(A + ((size_t)(m0 + row) * 1024 + k0 + cg * 8), As + c * 512);
      async16(W + ((size_t)(n0 + row) * 1024 + k0 + cg * 8), Bs + c * 512);
    }
    __syncthreads();
    h8 af[4], bf[4];
#pragma unroll
    for (int i = 0; i < 4; ++i)
      af[i] = *(const h8*)&As[(wm * 64 + i * 16 + l15) * 32 + quad * 8];
#pragma unroll
    for (int j = 0; j < 4; ++j)
      bf[j] = *(const h8*)&Bs[(wn * 64 + j * 16 + l15) * 32 + quad * 8];
#pragma unroll
    for (int i = 0; i < 4; ++i)
#pragma unroll
      for (int j = 0; j < 4; ++j)
        acc[i][j] = __builtin_amdgcn_mfma_f32_16x16x32_f16(af[i], bf[j], acc[i][j], 0, 0, 0);
    __syncthreads();
  }

  // epilogue: col cl -> (h, d, t); t=0 -> P (n-major), t=1 -> EKt, t=2 -> Vt
  const int b = m0 >> 12;
#pragma unroll
  for (int i = 0; i < 4; ++i) {
    const int rl = (m0 & 4095) + wm * 64 + i * 16 + quad * 4;  // local n in b
    const int rg = m0 + wm * 64 + i * 16 + quad * 4;           // global row
#pragma unroll
    for (int j = 0; j < 4; ++j) {
      const int cl = n0 + wn * 64 + j * 16 + l15;
      const int h = cl / 192;
      const int d3 = cl - h * 192;
      const int d = d3 / 3;
      const int t = d3 - d * 3;
      const size_t tr = ((size_t)((b * 16 + h) * 64 + d)) * 4096 + rl;
      if (t == 2) {
        h4 o = {(_Float16)acc[i][j][0], (_Float16)acc[i][j][1],
                (_Float16)acc[i][j][2], (_Float16)acc[i][j][3]};
        *(h4*)&Vt[tr] = o;
      } else if (t == 1) {
        h4 o;
#pragma unroll
        for (int r = 0; r < 4; ++r)
          o[r] = (_Float16)(mask[rg + r] ? __expf(acc[i][j][r]) : 0.f);
        *(h4*)&EKt[tr] = o;
      } else {
#pragma unroll
        for (int r = 0; r < 4; ++r)
          P[(size_t)(rg + r) * 1024 + h * 64 + d] =
              (_Float16)__expf(acc[i][j][r] * 0.125f);
      }
    }
  }
}

// ---------------- kernel 3: ctx partials, register-direct MFMA -----------
// grid (16 chunks, 64 bh). No LDS, no barriers. Wave w owns d in [16w,16w+16).
// part layout per (bh,chunk): 4096 acc[d][e] + 64 den[d].
__global__ __launch_bounds__(256) void ctx_partial(const _Float16* __restrict__ EKt,
                                                   const _Float16* __restrict__ Vt,
                                                   float* __restrict__ part) {
  const int chunk = blockIdx.x;  // 0..15
  const int bh = blockIdx.y;     // 0..63
  const int tid = threadIdx.x;
  const int lane = tid & 63, wid = tid >> 6;
  const int l15 = lane & 15, quad = lane >> 4;

  const f4 z = {0.f, 0.f, 0.f, 0.f};
  f4 acc[5];
#pragma unroll
  for (int i = 0; i < 5; ++i) acc[i] = z;

  h8 bones;
  {
    const _Float16 o1 = (l15 == 0) ? (_Float16)1.f : (_Float16)0.f;
#pragma unroll
    for (int j = 0; j < 8; ++j) bones[j] = o1;
  }

  const int ncol = chunk * 256 + quad * 8;
  const _Float16* ap = EKt + ((size_t)(bh * 64) + wid * 16 + l15) * 4096 + ncol;
  const _Float16* bp = Vt + ((size_t)(bh * 64) + l15) * 4096 + ncol;

#pragma unroll 2
  for (int s = 0; s < 8; ++s) {
    const int off = s * 32;
    h8 a = *(const h8*)(ap + off);
    h8 b0 = *(const h8*)(bp + off);
    h8 b1 = *(const h8*)(bp + (size_t)16 * 4096 + off);
    h8 b2 = *(const h8*)(bp + (size_t)32 * 4096 + off);
    h8 b3 = *(const h8*)(bp + (size_t)48 * 4096 + off);
    acc[0] = __builtin_amdgcn_mfma_f32_16x16x32_f16(a, b0, acc[0], 0, 0, 0);
    acc[1] = __builtin_amdgcn_mfma_f32_16x16x32_f16(a, b1, acc[1], 0, 0, 0);
    acc[2] = __builtin_amdgcn_mfma_f32_16x16x32_f16(a, b2, acc[2], 0, 0, 0);
    acc[3] = __builtin_amdgcn_mfma_f32_16x16x32_f16(a, b3, acc[3], 0, 0, 0);
    acc[4] = __builtin_amdgcn_mfma_f32_16x16x32_f16(a, bones, acc[4], 0, 0, 0);
  }

  const size_t pb = ((size_t)bh * 16 + chunk) * 4160;
  const int dw = wid * 16 + quad * 4;
#pragma unroll
  for (int et = 0; et < 4; ++et)
#pragma unroll
    for (int r = 0; r < 4; ++r)
      part[pb + (size_t)(dw + r) * 64 + et * 16 + l15] = acc[et][r];
  if (l15 == 0) {
#pragma unroll
    for (int r = 0; r < 4; ++r) part[pb + 4096 + dw + r] = acc[4][r];
  }
}

// ---------------- kernel 4: reduce partials + memkv (fp32), store ctx^T --
// ctxt[bh*4096 + e*64 + d]  (e-major, d-contig -> B-frag contiguous for attn)
__global__ __launch_bounds__(256) void reduce_ctx(const float* __restrict__ part,
                                                  const float* __restrict__ memkv,
                                                  _Float16* __restrict__ ctxt) {
  const int bh = blockIdx.x;
  const int h = bh & 15;
  const int tid = threadIdx.x;
  __shared__ float inv[64];
  const size_t pb = (size_t)bh * 16 * 4160;
  if (tid < 64) {
    float s = 0.f;
#pragma unroll
    for (int c = 0; c < 16; ++c) s += part[pb + (size_t)c * 4160 + 4096 + tid];
#pragma unroll
    for (int j = 0; j < 4; ++j) s += __expf(memkv[(h * 4 + j) * 64 + tid]);
    inv[tid] = 1.0f / s;
  }
  __syncthreads();
  const int d = tid >> 2, e0 = (tid & 3) * 16;
  float emk[4];
#pragma unroll
  for (int j = 0; j < 4; ++j) emk[j] = __expf(memkv[(h * 4 + j) * 64 + d]);
  f4 s[4];
#pragma unroll
  for (int g = 0; g < 4; ++g) s[g] = f4{0.f, 0.f, 0.f, 0.f};
#pragma unroll
  for (int c = 0; c < 16; ++c)
#pragma unroll
    for (int g = 0; g < 4; ++g)
      s[g] += *(const f4*)&part[pb + (size_t)c * 4160 + (size_t)d * 64 + e0 + g * 4];
#pragma unroll
  for (int j = 0; j < 4; ++j) {
#pragma unroll
    for (int g = 0; g < 4; ++g) {
      f4 mv = *(const f4*)&memkv[4096 + (h * 4 + j) * 64 + e0 + g * 4];
      s[g] += emk[j] * mv;
    }
  }
  const float iv = inv[d];
#pragma unroll
  for (int g = 0; g < 4; ++g)
#pragma unroll
    for (int u = 0; u < 4; ++u)
      ctxt[(size_t)bh * 4096 + (size_t)(e0 + g * 4 + u) * 64 + d] =
          (_Float16)(s[g][u] * iv);
}

// ---------------- kernel 5: out = (P @ ctx)/s, register-direct MFMA ------
// grid (128 l-chunks, 16 heads). No LDS, no barriers.
__global__ __launch_bounds__(256) void attn_out(const _Float16* __restrict__ P,
                                                const _Float16* __restrict__ ctxt,
                                                const int* __restrict__ mask,
                                                float* __restrict__ out) {
  const int l0 = blockIdx.x * 128;
  const int h = blockIdx.y;
  const int bh = (l0 >> 12) * 16 + h;
  const int tid = threadIdx.x;
  const int lane = tid & 63, wid = tid >> 6;
  const int l15 = lane & 15, quad = lane >> 4;

  h8 af[2][2], bf[2][4], bones;
  {
    const _Float16 o1 = (l15 == 0) ? (_Float16)1.f : (_Float16)0.f;
#pragma unroll
    for (int j = 0; j < 8; ++j) bones[j] = o1;
  }
#pragma unroll
  for (int i = 0; i < 2; ++i)
#pragma unroll
    for (int ks = 0; ks < 2; ++ks)
      af[i][ks] = *(const h8*)&P[(size_t)(l0 + wid * 32 + i * 16 + l15) * 1024 +
                                 h * 64 + ks * 32 + quad * 8];
#pragma unroll
  for (int ks = 0; ks < 2; ++ks)
#pragma unroll
    for (int et = 0; et < 4; ++et)
      bf[ks][et] = *(const h8*)&ctxt[(size_t)bh * 4096 +
                                     (size_t)(et * 16 + l15) * 64 + ks * 32 + quad * 8];

  const f4 z = {0.f, 0.f, 0.f, 0.f};
  f4 acc[2][5];
#pragma unroll
  for (int i = 0; i < 2; ++i)
#pragma unroll
    for (int j = 0; j < 5; ++j) acc[i][j] = z;
#pragma unroll
  for (int i = 0; i < 2; ++i)
#pragma unroll
    for (int ks = 0; ks < 2; ++ks) {
#pragma unroll
      for (int et = 0; et < 4; ++et)
        acc[i][et] = __builtin_amdgcn_mfma_f32_16x16x32_f16(af[i][ks], bf[ks][et], acc[i][et], 0, 0, 0);
      acc[i][4] = __builtin_amdgcn_mfma_f32_16x16x32_f16(af[i][ks], bones, acc[i][4], 0, 0, 0);
    }

#pragma unroll
  for (int i = 0; i < 2; ++i) {
#pragma unroll
    for (int r = 0; r < 4; ++r) {
      const int row = l0 + wid * 32 + i * 16 + quad * 4 + r;
      const float sb = __shfl(acc[i][4][r], lane & 48);  // den from col-0 lane
      const float iv = mask[row] ? 1.0f / sb : 0.0f;
#pragma unroll
      for (int et = 0; et < 4; ++et)
        out[(size_t)row * 1024 + h * 64 + et * 16 + l15] = acc[i][et][r] * iv;
    }
  }
}

// ---------------- launch ----------------
extern "C" void kernel_launch(void* const* d_in, const int* in_sizes, int n_in,
                              void* d_out, int out_size, void* d_ws, size_t ws_size,
                              hipStream_t stream) {
  const float* x = (const float*)d_in[0];      // 16777216
  const float* w = (const float*)d_in[1];      // 3145728
  const float* memkv = (const float*)d_in[2];  // 8192
  const int* mask = (const int*)d_in[3];       // 16384
  float* out = (float*)d_out;

  char* ws = (char*)d_ws;
  _Float16* xh   = (_Float16*)(ws + 0);           //  33,554,432
  _Float16* wh   = (_Float16*)(ws + 33554432);    //   6,291,456
  _Float16* P    = (_Float16*)(ws + 39845888);    //  33,554,432
  _Float16* EKt  = (_Float16*)(ws + 73400320);    //  33,554,432
  _Float16* Vt   = (_Float16*)(ws + 106954752);   //  33,554,432
  float*    part = (float*)(ws + 140509184);      //  17,039,360
  _Float16* ctxt = (_Float16*)(ws + 157548544);   //     524,288  (~150.8 MB)

  cvt_f16<<<dim3(19456), dim3(256), 0, stream>>>((const float4*)x, (const float4*)w,
                                                 (h4*)xh, (h4*)wh);
  gemm_qkv<<<dim3(24, 128), dim3(256), 0, stream>>>(xh, wh, mask, P, EKt, Vt);
  ctx_partial<<<dim3(16, 64), dim3(256), 0, stream>>>(EKt, Vt, part);
  reduce_ctx<<<dim3(64), dim3(256), 0, stream>>>(part, memkv, ctxt);
  attn_out<<<dim3(128, 16), dim3(256), 0, stream>>>(P, ctxt, mask, out);
}